// Round 10
// baseline (635.321 us; speedup 1.0000x reference)
//
#include <hip/hip_runtime.h>
#include <hip/hip_bf16.h>

#define NN 100000
#define EE 800000
#define HH 4
#define CC 64
#define GG 2000
#define NB 98           // scan blocks: ceil((NN/4)/256)

typedef unsigned short ushortx;
typedef __attribute__((ext_vector_type(8))) short short8;
typedef __attribute__((ext_vector_type(4))) float f32x4;

// ---------------- CSR build ----------------

__global__ void hist_kernel(const int* __restrict__ ei, int* __restrict__ deg) {
    int e = blockIdx.x * 256 + threadIdx.x;
    const int tot = EE + NN;
    if (e < tot) {
        int d = (e < EE) ? ei[EE + e] : (e - EE);
        atomicAdd(&deg[d], 1);
    }
}

__global__ void node_count(const int* __restrict__ batch, float* __restrict__ pcnt) {
    int n = blockIdx.x * 256 + threadIdx.x;
    if (n < NN) atomicAdd(&pcnt[batch[n]], 1.0f);
}

__global__ __launch_bounds__(256) void scan_blk(const int* __restrict__ deg,
                                                int* __restrict__ bsum) {
    const int t = threadIdx.x;
    const int idx4 = blockIdx.x * 256 + t;
    int4 v = {0, 0, 0, 0};
    if (idx4 < NN / 4) v = ((const int4*)deg)[idx4];
    int s = v.x + v.y + v.z + v.w;
#pragma unroll
    for (int m = 32; m; m >>= 1) s += __shfl_xor(s, m, 64);
    __shared__ int ws[4];
    if ((t & 63) == 0) ws[t >> 6] = s;
    __syncthreads();
    if (t == 0) bsum[blockIdx.x] = ws[0] + ws[1] + ws[2] + ws[3];
}

__global__ void scan_mid(const int* __restrict__ bsum, int* __restrict__ boff,
                         int* __restrict__ off) {
    __shared__ int sh[128];
    const int t = threadIdx.x;
    int v = (t < NB) ? bsum[t] : 0;
    sh[t] = v;
    __syncthreads();
    for (int d = 1; d < 128; d <<= 1) {
        int u = (t >= d) ? sh[t - d] : 0;
        __syncthreads();
        sh[t] += u;
        __syncthreads();
    }
    if (t < NB) boff[t] = sh[t] - v;
    if (t == NB - 1) off[NN] = sh[t];
}

__global__ __launch_bounds__(256) void scan_fin(const int* __restrict__ deg,
                                                const int* __restrict__ boff,
                                                int* __restrict__ off) {
    const int t = threadIdx.x;
    const int idx4 = blockIdx.x * 256 + t;
    int4 v = {0, 0, 0, 0};
    if (idx4 < NN / 4) v = ((const int4*)deg)[idx4];
    int s = v.x + v.y + v.z + v.w;
    const int lane = t & 63, w = t >> 6;
    int inc = s;
#pragma unroll
    for (int d = 1; d < 64; d <<= 1) {
        int u = __shfl_up(inc, d, 64);
        if (lane >= d) inc += u;
    }
    __shared__ int ws[4];
    if (lane == 63) ws[w] = inc;
    __syncthreads();
    int woff = 0;
    for (int i = 0; i < w; ++i) woff += ws[i];
    int excl = inc - s + woff + boff[blockIdx.x];
    if (idx4 < NN / 4) {
        int4 o;
        o.x = excl;
        o.y = o.x + v.x;
        o.z = o.y + v.y;
        o.w = o.z + v.z;
        ((int4*)off)[idx4] = o;
    }
}

__global__ void fill_kernel(const int* __restrict__ ei, const int* __restrict__ off,
                            int* __restrict__ cursor, int* __restrict__ csr_src) {
    int e = blockIdx.x * 256 + threadIdx.x;
    const int tot = EE + NN;
    if (e < tot) {
        int s, d;
        if (e < EE) { s = ei[e]; d = ei[EE + e]; }
        else        { s = e - EE; d = e - EE; }
        int p = off[d] + atomicAdd(&cursor[d], 1);
        csr_src[p] = s;
    }
}

__device__ __forceinline__ ushortx f2bf(float v) {
    __hip_bfloat16 b = __float2bfloat16(v);
    return *reinterpret_cast<ushortx*>(&b);
}

// ---------------- layer-1 GEMM (K=9), exact fp32 scalar path ----------------
// k-loop (step 3, bound k+2<K) covers k=0..8 COMPLETELY for K=9. No remainder.
// R=4: rows always valid since NN % 4 == 0 and row0 stride % 4 == 0.

__global__ __launch_bounds__(256) void gemm_att9(
    const float* __restrict__ X, const float* __restrict__ W,
    const float* __restrict__ a_s, const float* __restrict__ a_d,
    ushortx* __restrict__ Hb, float* __restrict__ ALS, float* __restrict__ ALD) {
    constexpr int K = 9, R = 4;
    const int c = threadIdx.x;
    const int lane = c & 63;
    const int wh = c >> 6;
    float wreg[K];
#pragma unroll
    for (int k = 0; k < K; ++k) wreg[k] = W[k * 256 + c];
    const float asv = a_s[c];
    const float adv = a_d[c];

    for (int row0 = blockIdx.x * R; row0 < NN; row0 += gridDim.x * R) {
        float p0[R], p1[R], p2[R];
#pragma unroll
        for (int r = 0; r < R; ++r) { p0[r] = p1[r] = p2[r] = 0.f; }
#pragma unroll
        for (int k = 0; k + 2 < K; k += 3) {
#pragma unroll
            for (int r = 0; r < R; ++r) {
                const float* xp = X + (size_t)(row0 + r) * K;
                p0[r] = fmaf(wreg[k + 0], xp[k + 0], p0[r]);
                p1[r] = fmaf(wreg[k + 1], xp[k + 1], p1[r]);
                p2[r] = fmaf(wreg[k + 2], xp[k + 2], p2[r]);
            }
        }
#pragma unroll
        for (int r = 0; r < R; ++r) {
            int row = row0 + r;
            float hv = (p0[r] + p1[r]) + p2[r];
            Hb[(size_t)row * 256 + c] = f2bf(hv);
            float sv = hv * asv;
            float dv = hv * adv;
#pragma unroll
            for (int m = 32; m; m >>= 1) {
                sv += __shfl_xor(sv, m, 64);
                dv += __shfl_xor(dv, m, 64);
            }
            if (lane == 0) {
                ALS[row * 4 + wh] = sv;
                ALD[row * 4 + wh] = dv;
            }
        }
    }
}

// ---------------- K=64 GEMM on matrix cores (bf16 MFMA) ----------------
// Verified layouts (learn_hip m89/m91/m120) for mfma_f32_16x16x32_bf16:
//   A[m=lane&15][k=(lane>>4)*8+j], B[k=(lane>>4)*8+j][n=lane&15],
//   D[row=(lane>>4)*4+reg][col=lane&15].

__global__ __launch_bounds__(256) void gemm64_mfma(
    const float* __restrict__ X, const float* __restrict__ W,
    const float* __restrict__ a_s, const float* __restrict__ a_d,
    ushortx* __restrict__ Hb, float* __restrict__ ALS, float* __restrict__ ALD) {
    __shared__ ushortx wt[16][2][64][8];   // [ct][kh][lane][j]  (32 KB)
    __shared__ ushortx xt[16][72];         // strip rows, padded pitch
    __shared__ float asld[256], adld[256];
    __shared__ float alsw[4][16], aldw[4][16];   // [head][row]

    const int tid = threadIdx.x;
    const int l = tid & 63, wv = tid >> 6;
    const int n = l & 15, q = l >> 4;

    asld[tid] = a_s[tid];
    adld[tid] = a_d[tid];
    for (int k = 0; k < 64; ++k) {
        float v = W[k * 256 + tid];
        int ct = tid >> 4, nn = tid & 15;
        int kh = k >> 5, qq = (k >> 3) & 3, jj = k & 7;
        wt[ct][kh][qq * 16 + nn][jj] = f2bf(v);
    }
    __syncthreads();

    for (int row0 = blockIdx.x * 16; row0 < NN; row0 += gridDim.x * 16) {
        {
            int r = tid >> 4, q4 = tid & 15;
            const float4 xv = *(const float4*)(X + (size_t)(row0 + r) * 64 + q4 * 4);
            ushortx* dst = &xt[r][q4 * 4];
            dst[0] = f2bf(xv.x); dst[1] = f2bf(xv.y);
            dst[2] = f2bf(xv.z); dst[3] = f2bf(xv.w);
        }
        __syncthreads();

        short8 a0 = *(const short8*)&xt[n][q * 8];        // k = 0..31 half
        short8 a1 = *(const short8*)&xt[n][32 + q * 8];   // k = 32..63 half

        float sv[4] = {0.f, 0.f, 0.f, 0.f};
        float dvv[4] = {0.f, 0.f, 0.f, 0.f};
#pragma unroll
        for (int ct = 0; ct < 4; ++ct) {
            const int ctg = wv * 4 + ct;
            short8 b0 = *(const short8*)&wt[ctg][0][l][0];
            short8 b1 = *(const short8*)&wt[ctg][1][l][0];
            f32x4 acc = {0.f, 0.f, 0.f, 0.f};
            acc = __builtin_amdgcn_mfma_f32_16x16x32_bf16(a0, b0, acc, 0, 0, 0);
            acc = __builtin_amdgcn_mfma_f32_16x16x32_bf16(a1, b1, acc, 0, 0, 0);
            const int col = ctg * 16 + n;
            const float asv = asld[col], adv = adld[col];
#pragma unroll
            for (int r = 0; r < 4; ++r) {
                const int row = row0 + q * 4 + r;
                Hb[(size_t)row * 256 + col] = f2bf(acc[r]);
                sv[r] = fmaf(acc[r], asv, sv[r]);
                dvv[r] = fmaf(acc[r], adv, dvv[r]);
            }
        }
#pragma unroll
        for (int m = 1; m <= 8; m <<= 1) {
#pragma unroll
            for (int r = 0; r < 4; ++r) {
                sv[r] += __shfl_xor(sv[r], m, 64);
                dvv[r] += __shfl_xor(dvv[r], m, 64);
            }
        }
        if (n == 0) {
#pragma unroll
            for (int r = 0; r < 4; ++r) {
                alsw[wv][q * 4 + r] = sv[r];
                aldw[wv][q * 4 + r] = dvv[r];
            }
        }
        __syncthreads();
        if (tid < 64) {
            int hh = tid & 3, rr = tid >> 2;
            ALS[(size_t)row0 * 4 + tid] = alsw[hh][rr];
            ALD[(size_t)row0 * 4 + tid] = aldw[hh][rr];
        }
        __syncthreads();
    }
}

// ---------------- fused softmax + aggregate (+ optional pooling) ------------
// Per 64-edge chunk: lane-parallel exp weights -> per-wave LDS table
// (padded [4][4][65], broadcast reads). Inner loop per edge: 1 index shuffle
// + 1 ds_read_b32 weight + 1 uint2 gather + 4 FMA. Unroll 8 for MLP.

template <bool LAST>
__global__ __launch_bounds__(256) void aggregate7(
    const ushortx* __restrict__ Hb, const float* __restrict__ ALS,
    const float* __restrict__ ALD, const int* __restrict__ off,
    const int* __restrict__ csr_src, const float* __restrict__ bias,
    float* __restrict__ OUT, const int* __restrict__ batch,
    float* __restrict__ psum) {
    const int wid = threadIdx.x >> 6;
    const int node = blockIdx.x * 4 + wid;
    const int l = threadIdx.x & 63;
    if (node >= NN) return;
    const int beg = off[node], end = off[node + 1];
    const int h = l >> 4;
    const uint2* hb2 = (const uint2*)Hb;   // row = 64 uint2 (256 bf16)
    const float4 aldv = ((const float4*)ALD)[node];
    __shared__ float lw[4][4][65];
    const float* lwh = &lw[wid][h][0];
    float4 acc = {0.f, 0.f, 0.f, 0.f};
    float4 dsum = {0.f, 0.f, 0.f, 0.f};

    for (int j0 = beg; j0 < end; j0 += 64) {
        const int cnt = min(64, end - j0);
        const int jj = j0 + l;
        int sv = 0;
        float4 w4 = {0.f, 0.f, 0.f, 0.f};
        if (jj < end) {
            sv = csr_src[jj];
            float4 a = ((const float4*)ALS)[sv];
            float vx = a.x + aldv.x, vy = a.y + aldv.y,
                  vz = a.z + aldv.z, vw = a.w + aldv.w;
            vx = (vx >= 0.f) ? vx : 0.2f * vx;
            vy = (vy >= 0.f) ? vy : 0.2f * vy;
            vz = (vz >= 0.f) ? vz : 0.2f * vz;
            vw = (vw >= 0.f) ? vw : 0.2f * vw;
            w4.x = expf(vx); w4.y = expf(vy); w4.z = expf(vz); w4.w = expf(vw);
        }
        dsum.x += w4.x; dsum.y += w4.y; dsum.z += w4.z; dsum.w += w4.w;
        lw[wid][0][l] = w4.x;
        lw[wid][1][l] = w4.y;
        lw[wid][2][l] = w4.z;
        lw[wid][3][l] = w4.w;

        int t = 0;
        for (; t + 8 <= cnt; t += 8) {
            int s[8];
            uint2 u[8];
#pragma unroll
            for (int k = 0; k < 8; ++k) s[k] = __shfl(sv, t + k, 64);
#pragma unroll
            for (int k = 0; k < 8; ++k) u[k] = hb2[(size_t)s[k] * 64 + l];
#pragma unroll
            for (int k = 0; k < 8; ++k) {
                float w = lwh[t + k];
                float c0 = __uint_as_float(u[k].x << 16);
                float c1 = __uint_as_float(u[k].x & 0xFFFF0000u);
                float c2 = __uint_as_float(u[k].y << 16);
                float c3 = __uint_as_float(u[k].y & 0xFFFF0000u);
                acc.x = fmaf(w, c0, acc.x);
                acc.y = fmaf(w, c1, acc.y);
                acc.z = fmaf(w, c2, acc.z);
                acc.w = fmaf(w, c3, acc.w);
            }
        }
        for (; t < cnt; ++t) {
            int s0 = __shfl(sv, t, 64);
            float w = lwh[t];
            uint2 u = hb2[(size_t)s0 * 64 + l];
            float c0 = __uint_as_float(u.x << 16);
            float c1 = __uint_as_float(u.x & 0xFFFF0000u);
            float c2 = __uint_as_float(u.y << 16);
            float c3 = __uint_as_float(u.y & 0xFFFF0000u);
            acc.x = fmaf(w, c0, acc.x);
            acc.y = fmaf(w, c1, acc.y);
            acc.z = fmaf(w, c2, acc.z);
            acc.w = fmaf(w, c3, acc.w);
        }
    }

#pragma unroll
    for (int m = 32; m; m >>= 1) {
        dsum.x += __shfl_xor(dsum.x, m, 64);
        dsum.y += __shfl_xor(dsum.y, m, 64);
        dsum.z += __shfl_xor(dsum.z, m, 64);
        dsum.w += __shfl_xor(dsum.w, m, 64);
    }
    float den = (h == 0) ? dsum.x : (h == 1) ? dsum.y : (h == 2) ? dsum.z : dsum.w;
    const float inv = 1.f / (den + 1e-16f);
    acc.x *= inv; acc.y *= inv; acc.z *= inv; acc.w *= inv;

#pragma unroll
    for (int m = 16; m <= 32; m <<= 1) {
        acc.x += __shfl_xor(acc.x, m, 64);
        acc.y += __shfl_xor(acc.y, m, 64);
        acc.z += __shfl_xor(acc.z, m, 64);
        acc.w += __shfl_xor(acc.w, m, 64);
    }
    if (l < 16) {
        float4 b4 = ((const float4*)bias)[l];
        float4 o;
        o.x = fmaxf(acc.x * 0.25f + b4.x, 0.f);
        o.y = fmaxf(acc.y * 0.25f + b4.y, 0.f);
        o.z = fmaxf(acc.z * 0.25f + b4.z, 0.f);
        o.w = fmaxf(acc.w * 0.25f + b4.w, 0.f);
        if constexpr (LAST) {
            int g = batch[node];
            float* pp = psum + (size_t)g * 64 + l * 4;
            atomicAdd(pp + 0, o.x);
            atomicAdd(pp + 1, o.y);
            atomicAdd(pp + 2, o.z);
            atomicAdd(pp + 3, o.w);
        } else {
            ((float4*)(OUT + (size_t)node * 64))[l] = o;
        }
    }
}

// ---------------- final linear ----------------

__global__ void pool_out(const float* __restrict__ psum, const float* __restrict__ pcnt,
                         const float* __restrict__ lw, const float* __restrict__ lb,
                         float* __restrict__ out) {
    int g = blockIdx.x * 4 + (threadIdx.x >> 6);
    int lane = threadIdx.x & 63;
    if (g < GG) {
        float cnt = fmaxf(pcnt[g], 1.0f);
        float v = psum[(size_t)g * 64 + lane] / cnt * lw[lane];
#pragma unroll
        for (int m = 32; m; m >>= 1) v += __shfl_xor(v, m, 64);
        if (lane == 0) out[g] = v + lb[0];
    }
}

// ---------------- launch ----------------

extern "C" void kernel_launch(void* const* d_in, const int* in_sizes, int n_in,
                              void* d_out, int out_size, void* d_ws, size_t ws_size,
                              hipStream_t stream) {
    const float* x     = (const float*)d_in[0];
    const int*   ei    = (const int*)d_in[1];
    const int*   batch = (const int*)d_in[2];
    const float* W1  = (const float*)d_in[3];
    const float* as1 = (const float*)d_in[4];
    const float* ad1 = (const float*)d_in[5];
    const float* b1  = (const float*)d_in[6];
    const float* W2  = (const float*)d_in[7];
    const float* as2 = (const float*)d_in[8];
    const float* ad2 = (const float*)d_in[9];
    const float* b2  = (const float*)d_in[10];
    const float* W3  = (const float*)d_in[11];
    const float* as3 = (const float*)d_in[12];
    const float* ad3 = (const float*)d_in[13];
    const float* b3  = (const float*)d_in[14];
    const float* lw  = (const float*)d_in[15];
    const float* lb  = (const float*)d_in[16];
    float* out = (float*)d_out;

    char* p = (char*)d_ws;
    auto carve = [&](size_t bytes) -> void* {
        void* r = (void*)p;
        p += (bytes + 255) & ~(size_t)255;
        return r;
    };
    int*     off    = (int*)carve((NN + 4) * sizeof(int));
    int*     deg    = (int*)carve(NN * sizeof(int));
    int*     cursor = (int*)carve(NN * sizeof(int));
    int*     bsum   = (int*)carve(NB * sizeof(int));
    int*     boff   = (int*)carve(NB * sizeof(int));
    int*     csr    = (int*)carve((size_t)(EE + NN) * sizeof(int));
    ushortx* hbuf   = (ushortx*)carve((size_t)NN * 256 * sizeof(ushortx));
    float*   fa     = (float*)carve((size_t)NN * 64 * sizeof(float));
    float*   als    = (float*)carve((size_t)NN * 4 * sizeof(float));
    float*   ald    = (float*)carve((size_t)NN * 4 * sizeof(float));
    float*   psum   = (float*)carve((size_t)GG * 64 * sizeof(float));
    float*   pcnt   = (float*)carve(GG * sizeof(float));

    hipMemsetAsync(deg, 0, NN * sizeof(int), stream);
    hipMemsetAsync(cursor, 0, NN * sizeof(int), stream);
    hipMemsetAsync(psum, 0, (size_t)GG * 64 * sizeof(float), stream);
    hipMemsetAsync(pcnt, 0, GG * sizeof(float), stream);

    const int etot = EE + NN;
    const int eblocks = (etot + 255) / 256;
    hist_kernel<<<eblocks, 256, 0, stream>>>(ei, deg);
    node_count<<<(NN + 255) / 256, 256, 0, stream>>>(batch, pcnt);
    scan_blk<<<NB, 256, 0, stream>>>(deg, bsum);
    scan_mid<<<1, 128, 0, stream>>>(bsum, boff, off);
    scan_fin<<<NB, 256, 0, stream>>>(deg, boff, off);
    fill_kernel<<<eblocks, 256, 0, stream>>>(ei, off, cursor, csr);

    const int ablocks = (NN + 3) / 4;
    // layer 1 (exact fp32 path, K=9)
    gemm_att9<<<2048, 256, 0, stream>>>(x, W1, as1, ad1, hbuf, als, ald);
    aggregate7<false><<<ablocks, 256, 0, stream>>>(hbuf, als, ald, off, csr, b1,
                                                   fa, batch, psum);
    // layer 2 (MFMA)
    gemm64_mfma<<<1024, 256, 0, stream>>>(fa, W2, as2, ad2, hbuf, als, ald);
    aggregate7<false><<<ablocks, 256, 0, stream>>>(hbuf, als, ald, off, csr, b2,
                                                   fa, batch, psum);
    // layer 3 (MFMA, pooling fused)
    gemm64_mfma<<<1024, 256, 0, stream>>>(fa, W3, as3, ad3, hbuf, als, ald);
    aggregate7<true><<<ablocks, 256, 0, stream>>>(hbuf, als, ald, off, csr, b3,
                                                  nullptr, batch, psum);

    pool_out<<<(GG + 3) / 4, 256, 0, stream>>>(psum, pcnt, lw, lb, out);
}

// Round 11
// 600.032 us; speedup vs baseline: 1.0588x; 1.0588x over previous
//
#include <hip/hip_runtime.h>
#include <hip/hip_bf16.h>

#define NN 100000
#define EE 800000
#define HH 4
#define CC 64
#define GG 2000
#define NB 98           // scan blocks: ceil((NN/4)/256)

typedef unsigned short ushortx;
typedef __attribute__((ext_vector_type(8))) short short8;
typedef __attribute__((ext_vector_type(4))) float f32x4;

// ---------------- CSR build ----------------

__global__ void hist_kernel(const int* __restrict__ ei, int* __restrict__ deg) {
    int e = blockIdx.x * 256 + threadIdx.x;
    const int tot = EE + NN;
    if (e < tot) {
        int d = (e < EE) ? ei[EE + e] : (e - EE);
        atomicAdd(&deg[d], 1);
    }
}

__global__ void node_count(const int* __restrict__ batch, float* __restrict__ pcnt) {
    int n = blockIdx.x * 256 + threadIdx.x;
    if (n < NN) atomicAdd(&pcnt[batch[n]], 1.0f);
}

__global__ __launch_bounds__(256) void scan_blk(const int* __restrict__ deg,
                                                int* __restrict__ bsum) {
    const int t = threadIdx.x;
    const int idx4 = blockIdx.x * 256 + t;
    int4 v = {0, 0, 0, 0};
    if (idx4 < NN / 4) v = ((const int4*)deg)[idx4];
    int s = v.x + v.y + v.z + v.w;
#pragma unroll
    for (int m = 32; m; m >>= 1) s += __shfl_xor(s, m, 64);
    __shared__ int ws[4];
    if ((t & 63) == 0) ws[t >> 6] = s;
    __syncthreads();
    if (t == 0) bsum[blockIdx.x] = ws[0] + ws[1] + ws[2] + ws[3];
}

__global__ void scan_mid(const int* __restrict__ bsum, int* __restrict__ boff,
                         int* __restrict__ off) {
    __shared__ int sh[128];
    const int t = threadIdx.x;
    int v = (t < NB) ? bsum[t] : 0;
    sh[t] = v;
    __syncthreads();
    for (int d = 1; d < 128; d <<= 1) {
        int u = (t >= d) ? sh[t - d] : 0;
        __syncthreads();
        sh[t] += u;
        __syncthreads();
    }
    if (t < NB) boff[t] = sh[t] - v;
    if (t == NB - 1) off[NN] = sh[t];
}

__global__ __launch_bounds__(256) void scan_fin(const int* __restrict__ deg,
                                                const int* __restrict__ boff,
                                                int* __restrict__ off) {
    const int t = threadIdx.x;
    const int idx4 = blockIdx.x * 256 + t;
    int4 v = {0, 0, 0, 0};
    if (idx4 < NN / 4) v = ((const int4*)deg)[idx4];
    int s = v.x + v.y + v.z + v.w;
    const int lane = t & 63, w = t >> 6;
    int inc = s;
#pragma unroll
    for (int d = 1; d < 64; d <<= 1) {
        int u = __shfl_up(inc, d, 64);
        if (lane >= d) inc += u;
    }
    __shared__ int ws[4];
    if (lane == 63) ws[w] = inc;
    __syncthreads();
    int woff = 0;
    for (int i = 0; i < w; ++i) woff += ws[i];
    int excl = inc - s + woff + boff[blockIdx.x];
    if (idx4 < NN / 4) {
        int4 o;
        o.x = excl;
        o.y = o.x + v.x;
        o.z = o.y + v.y;
        o.w = o.z + v.z;
        ((int4*)off)[idx4] = o;
    }
}

__global__ void fill_kernel(const int* __restrict__ ei, const int* __restrict__ off,
                            int* __restrict__ cursor, int* __restrict__ csr_src) {
    int e = blockIdx.x * 256 + threadIdx.x;
    const int tot = EE + NN;
    if (e < tot) {
        int s, d;
        if (e < EE) { s = ei[e]; d = ei[EE + e]; }
        else        { s = e - EE; d = e - EE; }
        int p = off[d] + atomicAdd(&cursor[d], 1);
        csr_src[p] = s;
    }
}

__device__ __forceinline__ ushortx f2bf(float v) {
    __hip_bfloat16 b = __float2bfloat16(v);
    return *reinterpret_cast<ushortx*>(&b);
}

// ---------------- attention-vector precompute ----------------
// va[k][comp] with comp = sd*4 + h:  va_s = W @ a_s per head (and a_d).
// al_s[n,h] = x[n,:] . va[:,h]  (pure reassociation of the reference sum).

__global__ void prep_va(const float* __restrict__ W, const float* __restrict__ as_,
                        const float* __restrict__ ad_, float* __restrict__ va,
                        int K) {
    int id = blockIdx.x * 256 + threadIdx.x;
    if (id >= K * 8) return;
    int k = id >> 3, comp = id & 7;
    int h = comp & 3, sd = comp >> 2;
    const float* a = sd ? ad_ : as_;
    const float* wrow = W + k * 256 + h * 64;
    const float* arow = a + h * 64;
    float s = 0.f;
    for (int c = 0; c < 64; ++c) s = fmaf(wrow[c], arow[c], s);
    va[k * 8 + comp] = s;
}

// ALS/ALD for one layer: thread = node, va broadcast from LDS.
template <int K>
__global__ __launch_bounds__(256) void att_gemv(
    const float* __restrict__ X, const float* __restrict__ va,
    float* __restrict__ ALS, float* __restrict__ ALD) {
    __shared__ float vs[K][8];
    const int tid = threadIdx.x;
    for (int i = tid; i < K * 8; i += 256) vs[i >> 3][i & 7] = va[i];
    __syncthreads();
    int n = blockIdx.x * 256 + tid;
    if (n >= NN) return;
    const float* xp = X + (size_t)n * K;
    float s0 = 0, s1 = 0, s2 = 0, s3 = 0, d0 = 0, d1 = 0, d2 = 0, d3 = 0;
    if constexpr (K % 4 == 0) {
#pragma unroll
        for (int q = 0; q < K / 4; ++q) {
            float4 xv = ((const float4*)xp)[q];
#pragma unroll
            for (int i = 0; i < 4; ++i) {
                float x1 = (i == 0) ? xv.x : (i == 1) ? xv.y : (i == 2) ? xv.z : xv.w;
                const float4 vsv = *(const float4*)&vs[4 * q + i][0];
                const float4 vdv = *(const float4*)&vs[4 * q + i][4];
                s0 = fmaf(x1, vsv.x, s0); s1 = fmaf(x1, vsv.y, s1);
                s2 = fmaf(x1, vsv.z, s2); s3 = fmaf(x1, vsv.w, s3);
                d0 = fmaf(x1, vdv.x, d0); d1 = fmaf(x1, vdv.y, d1);
                d2 = fmaf(x1, vdv.z, d2); d3 = fmaf(x1, vdv.w, d3);
            }
        }
    } else {
#pragma unroll
        for (int k = 0; k < K; ++k) {
            float x1 = xp[k];
            const float4 vsv = *(const float4*)&vs[k][0];
            const float4 vdv = *(const float4*)&vs[k][4];
            s0 = fmaf(x1, vsv.x, s0); s1 = fmaf(x1, vsv.y, s1);
            s2 = fmaf(x1, vsv.z, s2); s3 = fmaf(x1, vsv.w, s3);
            d0 = fmaf(x1, vdv.x, d0); d1 = fmaf(x1, vdv.y, d1);
            d2 = fmaf(x1, vdv.z, d2); d3 = fmaf(x1, vdv.w, d3);
        }
    }
    float4 so = {s0, s1, s2, s3}, dd = {d0, d1, d2, d3};
    ((float4*)ALS)[n] = so;
    ((float4*)ALD)[n] = dd;
}

// ---------------- layer-1 GEMM (K=9), exact fp32, pure GEMM ----------------
// k-loop (step 3, bound k+2<K) covers k=0..8 COMPLETELY for K=9. No remainder.

__global__ __launch_bounds__(256) void gemm9(
    const float* __restrict__ X, const float* __restrict__ W,
    ushortx* __restrict__ Hb) {
    constexpr int K = 9, R = 4;
    const int c = threadIdx.x;
    float wreg[K];
#pragma unroll
    for (int k = 0; k < K; ++k) wreg[k] = W[k * 256 + c];

    for (int row0 = blockIdx.x * R; row0 < NN; row0 += gridDim.x * R) {
        float p0[R], p1[R], p2[R];
#pragma unroll
        for (int r = 0; r < R; ++r) { p0[r] = p1[r] = p2[r] = 0.f; }
#pragma unroll
        for (int k = 0; k + 2 < K; k += 3) {
#pragma unroll
            for (int r = 0; r < R; ++r) {
                const float* xp = X + (size_t)(row0 + r) * K;
                p0[r] = fmaf(wreg[k + 0], xp[k + 0], p0[r]);
                p1[r] = fmaf(wreg[k + 1], xp[k + 1], p1[r]);
                p2[r] = fmaf(wreg[k + 2], xp[k + 2], p2[r]);
            }
        }
#pragma unroll
        for (int r = 0; r < R; ++r) {
            float hv = (p0[r] + p1[r]) + p2[r];
            Hb[(size_t)(row0 + r) * 256 + c] = f2bf(hv);
        }
    }
}

// ---------------- K=64 GEMM on matrix cores (bf16 MFMA), pure GEMM ----------
// Verified layouts (learn_hip m89/m91/m120) for mfma_f32_16x16x32_bf16:
//   A[m=lane&15][k=(lane>>4)*8+j], B[k=(lane>>4)*8+j][n=lane&15],
//   D[row=(lane>>4)*4+reg][col=lane&15].

__global__ __launch_bounds__(256) void gemm64_mfma(
    const float* __restrict__ X, const float* __restrict__ W,
    ushortx* __restrict__ Hb) {
    __shared__ ushortx wt[16][2][64][8];   // [ct][kh][lane][j]  (32 KB)
    __shared__ ushortx xt[16][72];         // strip rows, padded pitch

    const int tid = threadIdx.x;
    const int l = tid & 63, wv = tid >> 6;
    const int n = l & 15, q = l >> 4;

    for (int k = 0; k < 64; ++k) {
        float v = W[k * 256 + tid];
        int ct = tid >> 4, nn = tid & 15;
        int kh = k >> 5, qq = (k >> 3) & 3, jj = k & 7;
        wt[ct][kh][qq * 16 + nn][jj] = f2bf(v);
    }
    __syncthreads();

    for (int row0 = blockIdx.x * 16; row0 < NN; row0 += gridDim.x * 16) {
        {
            int r = tid >> 4, q4 = tid & 15;
            const float4 xv = *(const float4*)(X + (size_t)(row0 + r) * 64 + q4 * 4);
            ushortx* dst = &xt[r][q4 * 4];
            dst[0] = f2bf(xv.x); dst[1] = f2bf(xv.y);
            dst[2] = f2bf(xv.z); dst[3] = f2bf(xv.w);
        }
        __syncthreads();

        short8 a0 = *(const short8*)&xt[n][q * 8];        // k = 0..31 half
        short8 a1 = *(const short8*)&xt[n][32 + q * 8];   // k = 32..63 half

#pragma unroll
        for (int ct = 0; ct < 4; ++ct) {
            const int ctg = wv * 4 + ct;
            short8 b0 = *(const short8*)&wt[ctg][0][l][0];
            short8 b1 = *(const short8*)&wt[ctg][1][l][0];
            f32x4 acc = {0.f, 0.f, 0.f, 0.f};
            acc = __builtin_amdgcn_mfma_f32_16x16x32_bf16(a0, b0, acc, 0, 0, 0);
            acc = __builtin_amdgcn_mfma_f32_16x16x32_bf16(a1, b1, acc, 0, 0, 0);
            const int col = ctg * 16 + n;
#pragma unroll
            for (int r = 0; r < 4; ++r) {
                const int row = row0 + q * 4 + r;
                Hb[(size_t)row * 256 + col] = f2bf(acc[r]);
            }
        }
        __syncthreads();
    }
}

// ---------------- fused softmax + aggregate (+ optional pooling) ------------
// R9-proven form: shuffle broadcast, unroll-4, bf16 uint2 gathers.

template <bool LAST>
__global__ __launch_bounds__(256) void aggregate6(
    const ushortx* __restrict__ Hb, const float* __restrict__ ALS,
    const float* __restrict__ ALD, const int* __restrict__ off,
    const int* __restrict__ csr_src, const float* __restrict__ bias,
    float* __restrict__ OUT, const int* __restrict__ batch,
    float* __restrict__ psum) {
    const int node = blockIdx.x * 4 + (threadIdx.x >> 6);
    const int l = threadIdx.x & 63;
    if (node >= NN) return;
    const int beg = off[node], end = off[node + 1];
    const int h = l >> 4;
    const uint2* hb2 = (const uint2*)Hb;   // row = 64 uint2 (256 bf16)
    const float4 aldv = ((const float4*)ALD)[node];
    float4 acc = {0.f, 0.f, 0.f, 0.f};
    float4 dsum = {0.f, 0.f, 0.f, 0.f};

    for (int j0 = beg; j0 < end; j0 += 64) {
        const int cnt = min(64, end - j0);
        const int jj = j0 + l;
        int sv = 0;
        float4 w4 = {0.f, 0.f, 0.f, 0.f};
        if (jj < end) {
            sv = csr_src[jj];
            float4 a = ((const float4*)ALS)[sv];
            float vx = a.x + aldv.x, vy = a.y + aldv.y,
                  vz = a.z + aldv.z, vw = a.w + aldv.w;
            vx = (vx >= 0.f) ? vx : 0.2f * vx;
            vy = (vy >= 0.f) ? vy : 0.2f * vy;
            vz = (vz >= 0.f) ? vz : 0.2f * vz;
            vw = (vw >= 0.f) ? vw : 0.2f * vw;
            w4.x = expf(vx); w4.y = expf(vy); w4.z = expf(vz); w4.w = expf(vw);
        }
        dsum.x += w4.x; dsum.y += w4.y; dsum.z += w4.z; dsum.w += w4.w;

        int t = 0;
        for (; t + 4 <= cnt; t += 4) {
            int s0 = __shfl(sv, t, 64);
            int s1 = __shfl(sv, t + 1, 64);
            int s2 = __shfl(sv, t + 2, 64);
            int s3 = __shfl(sv, t + 3, 64);
            uint2 u0 = hb2[(size_t)s0 * 64 + l];
            uint2 u1 = hb2[(size_t)s1 * 64 + l];
            uint2 u2 = hb2[(size_t)s2 * 64 + l];
            uint2 u3 = hb2[(size_t)s3 * 64 + l];
#pragma unroll
            for (int k = 0; k < 4; ++k) {
                int tt = t + k;
                float ax = __shfl(w4.x, tt, 64), ay = __shfl(w4.y, tt, 64),
                      az = __shfl(w4.z, tt, 64), aw = __shfl(w4.w, tt, 64);
                float w = (h == 0) ? ax : (h == 1) ? ay : (h == 2) ? az : aw;
                uint2 u = (k == 0) ? u0 : (k == 1) ? u1 : (k == 2) ? u2 : u3;
                float c0 = __uint_as_float(u.x << 16);
                float c1 = __uint_as_float(u.x & 0xFFFF0000u);
                float c2 = __uint_as_float(u.y << 16);
                float c3 = __uint_as_float(u.y & 0xFFFF0000u);
                acc.x = fmaf(w, c0, acc.x);
                acc.y = fmaf(w, c1, acc.y);
                acc.z = fmaf(w, c2, acc.z);
                acc.w = fmaf(w, c3, acc.w);
            }
        }
        for (; t < cnt; ++t) {
            int s0 = __shfl(sv, t, 64);
            float ax = __shfl(w4.x, t, 64), ay = __shfl(w4.y, t, 64),
                  az = __shfl(w4.z, t, 64), aw = __shfl(w4.w, t, 64);
            float w = (h == 0) ? ax : (h == 1) ? ay : (h == 2) ? az : aw;
            uint2 u = hb2[(size_t)s0 * 64 + l];
            float c0 = __uint_as_float(u.x << 16);
            float c1 = __uint_as_float(u.x & 0xFFFF0000u);
            float c2 = __uint_as_float(u.y << 16);
            float c3 = __uint_as_float(u.y & 0xFFFF0000u);
            acc.x = fmaf(w, c0, acc.x);
            acc.y = fmaf(w, c1, acc.y);
            acc.z = fmaf(w, c2, acc.z);
            acc.w = fmaf(w, c3, acc.w);
        }
    }

#pragma unroll
    for (int m = 32; m; m >>= 1) {
        dsum.x += __shfl_xor(dsum.x, m, 64);
        dsum.y += __shfl_xor(dsum.y, m, 64);
        dsum.z += __shfl_xor(dsum.z, m, 64);
        dsum.w += __shfl_xor(dsum.w, m, 64);
    }
    float den = (h == 0) ? dsum.x : (h == 1) ? dsum.y : (h == 2) ? dsum.z : dsum.w;
    const float inv = 1.f / (den + 1e-16f);
    acc.x *= inv; acc.y *= inv; acc.z *= inv; acc.w *= inv;

#pragma unroll
    for (int m = 16; m <= 32; m <<= 1) {
        acc.x += __shfl_xor(acc.x, m, 64);
        acc.y += __shfl_xor(acc.y, m, 64);
        acc.z += __shfl_xor(acc.z, m, 64);
        acc.w += __shfl_xor(acc.w, m, 64);
    }
    if (l < 16) {
        float4 b4 = ((const float4*)bias)[l];
        float4 o;
        o.x = fmaxf(acc.x * 0.25f + b4.x, 0.f);
        o.y = fmaxf(acc.y * 0.25f + b4.y, 0.f);
        o.z = fmaxf(acc.z * 0.25f + b4.z, 0.f);
        o.w = fmaxf(acc.w * 0.25f + b4.w, 0.f);
        if constexpr (LAST) {
            int g = batch[node];
            float* pp = psum + (size_t)g * 64 + l * 4;
            atomicAdd(pp + 0, o.x);
            atomicAdd(pp + 1, o.y);
            atomicAdd(pp + 2, o.z);
            atomicAdd(pp + 3, o.w);
        } else {
            ((float4*)(OUT + (size_t)node * 64))[l] = o;
        }
    }
}

// ---------------- final linear ----------------

__global__ void pool_out(const float* __restrict__ psum, const float* __restrict__ pcnt,
                         const float* __restrict__ lw, const float* __restrict__ lb,
                         float* __restrict__ out) {
    int g = blockIdx.x * 4 + (threadIdx.x >> 6);
    int lane = threadIdx.x & 63;
    if (g < GG) {
        float cnt = fmaxf(pcnt[g], 1.0f);
        float v = psum[(size_t)g * 64 + lane] / cnt * lw[lane];
#pragma unroll
        for (int m = 32; m; m >>= 1) v += __shfl_xor(v, m, 64);
        if (lane == 0) out[g] = v + lb[0];
    }
}

// ---------------- launch ----------------

extern "C" void kernel_launch(void* const* d_in, const int* in_sizes, int n_in,
                              void* d_out, int out_size, void* d_ws, size_t ws_size,
                              hipStream_t stream) {
    const float* x     = (const float*)d_in[0];
    const int*   ei    = (const int*)d_in[1];
    const int*   batch = (const int*)d_in[2];
    const float* W1  = (const float*)d_in[3];
    const float* as1 = (const float*)d_in[4];
    const float* ad1 = (const float*)d_in[5];
    const float* b1  = (const float*)d_in[6];
    const float* W2  = (const float*)d_in[7];
    const float* as2 = (const float*)d_in[8];
    const float* ad2 = (const float*)d_in[9];
    const float* b2  = (const float*)d_in[10];
    const float* W3  = (const float*)d_in[11];
    const float* as3 = (const float*)d_in[12];
    const float* ad3 = (const float*)d_in[13];
    const float* b3  = (const float*)d_in[14];
    const float* lw  = (const float*)d_in[15];
    const float* lb  = (const float*)d_in[16];
    float* out = (float*)d_out;

    char* p = (char*)d_ws;
    auto carve = [&](size_t bytes) -> void* {
        void* r = (void*)p;
        p += (bytes + 255) & ~(size_t)255;
        return r;
    };
    int*     off    = (int*)carve((NN + 4) * sizeof(int));
    int*     deg    = (int*)carve(NN * sizeof(int));
    int*     cursor = (int*)carve(NN * sizeof(int));
    int*     bsum   = (int*)carve(NB * sizeof(int));
    int*     boff   = (int*)carve(NB * sizeof(int));
    int*     csr    = (int*)carve((size_t)(EE + NN) * sizeof(int));
    ushortx* hbuf   = (ushortx*)carve((size_t)NN * 256 * sizeof(ushortx));
    float*   fa     = (float*)carve((size_t)NN * 64 * sizeof(float));
    float*   als    = (float*)carve((size_t)NN * 4 * sizeof(float));
    float*   ald    = (float*)carve((size_t)NN * 4 * sizeof(float));
    float*   psum   = (float*)carve((size_t)GG * 64 * sizeof(float));
    float*   pcnt   = (float*)carve(GG * sizeof(float));
    float*   va1    = (float*)carve(9 * 8 * sizeof(float));
    float*   va2    = (float*)carve(64 * 8 * sizeof(float));
    float*   va3    = (float*)carve(64 * 8 * sizeof(float));

    hipMemsetAsync(deg, 0, NN * sizeof(int), stream);
    hipMemsetAsync(cursor, 0, NN * sizeof(int), stream);
    hipMemsetAsync(psum, 0, (size_t)GG * 64 * sizeof(float), stream);
    hipMemsetAsync(pcnt, 0, GG * sizeof(float), stream);

    const int etot = EE + NN;
    const int eblocks = (etot + 255) / 256;
    hist_kernel<<<eblocks, 256, 0, stream>>>(ei, deg);
    node_count<<<(NN + 255) / 256, 256, 0, stream>>>(batch, pcnt);
    scan_blk<<<NB, 256, 0, stream>>>(deg, bsum);
    scan_mid<<<1, 128, 0, stream>>>(bsum, boff, off);
    scan_fin<<<NB, 256, 0, stream>>>(deg, boff, off);
    fill_kernel<<<eblocks, 256, 0, stream>>>(ei, off, cursor, csr);

    prep_va<<<1, 256, 0, stream>>>(W1, as1, ad1, va1, 9);
    prep_va<<<2, 256, 0, stream>>>(W2, as2, ad2, va2, 64);
    prep_va<<<2, 256, 0, stream>>>(W3, as3, ad3, va3, 64);

    const int ablocks = (NN + 3) / 4;
    const int nblocks = (NN + 255) / 256;
    // layer 1 (exact fp32 GEMM, K=9)
    gemm9<<<2048, 256, 0, stream>>>(x, W1, hbuf);
    att_gemv<9><<<nblocks, 256, 0, stream>>>(x, va1, als, ald);
    aggregate6<false><<<ablocks, 256, 0, stream>>>(hbuf, als, ald, off, csr, b1,
                                                   fa, batch, psum);
    // layer 2 (MFMA)
    gemm64_mfma<<<1024, 256, 0, stream>>>(fa, W2, hbuf);
    att_gemv<64><<<nblocks, 256, 0, stream>>>(fa, va2, als, ald);
    aggregate6<false><<<ablocks, 256, 0, stream>>>(hbuf, als, ald, off, csr, b2,
                                                   fa, batch, psum);
    // layer 3 (MFMA, pooling fused)
    gemm64_mfma<<<1024, 256, 0, stream>>>(fa, W3, hbuf);
    att_gemv<64><<<nblocks, 256, 0, stream>>>(fa, va3, als, ald);
    aggregate6<true><<<ablocks, 256, 0, stream>>>(hbuf, als, ald, off, csr, b3,
                                                  nullptr, batch, psum);

    pool_out<<<(GG + 3) / 4, 256, 0, stream>>>(psum, pcnt, lw, lb, out);
}